// Round 6
// baseline (101.325 us; speedup 1.0000x reference)
//
#include <hip/hip_runtime.h>
#include <hip/hip_bf16.h>
#include <math.h>

// PhaseMLP fused, R9: register-direct B (no LDS round-trip for weights).
//   y[b,o] = sum_k c_k(b) * ( x[b,:] @ W_k + b_k )
// R8 post-mortem: decorrelation hurt -> L2 hotspot theory dead. Re-costing
// R6: the B LDS round-trip (1MB DMA write + 1.25MB ds_read back, sharing
// banks) is ~13-14us of the 28us k_fused all by itself, plus ~4us of
// exposed latency from the 1-chunk-deep VMW4 ping-pong. R5's reg-direct
// form was abandoned on a miscalculation (in-flight is 12KB/wave =
// 192KB/CU, not 3KB; R5 was slow because it used 128 blocks -> half the
// CUs idle). R9 = reg-direct B at 256 blocks x 16 waves x M=16:
//   - per-wave rotating 3-chunk register pipeline (pre[3][4] bf16x8,
//     48 VGPR): MFMA B operands come straight from global loads; compiler
//     emits counted vmcnt off the register scoreboard.
//   - LDS holds only activations (~29KB); raw s_barrier + lgkmcnt(0) at
//     layer boundaries keeps prefetch in flight across layers.
//   - bias folded into accumulator init (acc_k = b_k; L2 kh==0 only).
//   - k_wt_all reshaped 512x256 -> 128x1024 (4 tile-teams per block).

typedef __attribute__((ext_vector_type(8))) short bf16x8;
typedef __attribute__((ext_vector_type(4))) float f32x4;

// LDS layout (bytes)
#define LDS_A0  0                   // 16 rows x 256B = 4096
#define LDS_A1  4096                // 16 rows x 512B = 8192
#define LDS_A2  12288               // 16 rows x 512B = 8192
#define LDS_RED 20480               // [8][16][17] fp32 = 8704
#define LDS_TOT (20480 + 8704)

static __device__ __forceinline__ void bar_lgkm() {
  asm volatile("s_waitcnt lgkmcnt(0)" ::: "memory");
  __builtin_amdgcn_s_barrier();
  asm volatile("" ::: "memory");
}

static __device__ __forceinline__ unsigned short f2bf(float f) {
  union { float f; unsigned int u; } v; v.f = f;
  unsigned int r = v.u + 0x7fffu + ((v.u >> 16) & 1u);  // RNE
  return (unsigned short)(r >> 16);
}

// Catmull-Rom basis coeffs in ABSOLUTE anchor order (c[0..3] for anchors 0..3)
static __device__ __forceinline__ void catmull(float ph, float c[4]) {
  float t = 4.0f * ph;
  float ft = floorf(t);
  int i1 = ((int)ft) & 3;
  float w = t - ft;
  float w2 = w * w, w3 = w2 * w;
  float r0 = -0.5f * w + w2 - 0.5f * w3;
  float r1 = 1.0f - 2.5f * w2 + 1.5f * w3;
  float r2 = 0.5f * w + 2.0f * w2 - 1.5f * w3;
  float r3 = -0.5f * w2 + 0.5f * w3;
  c[(i1 + 3) & 3] = r0;
  c[i1]           = r1;
  c[(i1 + 1) & 3] = r2;
  c[(i1 + 2) & 3] = r3;
}

// ---------------------------------------------------------------------------
// Prep: transpose+convert all three weight tensors (fp32 [4K,O] -> bf16 [O,4K])
// 128 blocks x (32,32): 4 tile-teams of (32,8) per block, 512 tiles total.
// ---------------------------------------------------------------------------
__global__ __launch_bounds__(1024) void k_wt_all(
    const float* __restrict__ w0, const float* __restrict__ w1,
    const float* __restrict__ w2, unsigned short* __restrict__ t0,
    unsigned short* __restrict__ t1, unsigned short* __restrict__ t2) {
  __shared__ float tile[4][32][33];
  const int team = threadIdx.y >> 3;      // 0..3
  const int tyy = threadIdx.y & 7;        // 0..7
  const int tx = threadIdx.x;             // 0..31
  const int bid = blockIdx.x * 4 + team;  // 0..511
  const float* W; unsigned short* T; int R, C, idx;
  if (bid < 128)      { W = w0; T = t0; R = 512;  C = 256; idx = bid; }
  else if (bid < 384) { W = w1; T = t1; R = 1024; C = 256; idx = bid - 128; }
  else                { W = w2; T = t2; R = 1024; C = 128; idx = bid - 384; }
  const int ntc = C >> 5;
  const int tr = (idx / ntc) << 5;
  const int tc = (idx % ntc) << 5;
#pragma unroll
  for (int j = tyy; j < 32; j += 8)
    tile[team][j][tx] = W[(size_t)(tr + j) * C + (tc + tx)];
  __syncthreads();
#pragma unroll
  for (int j = tyy; j < 32; j += 8)
    T[(size_t)(tc + j) * R + (tr + tx)] = f2bf(tile[team][tx][j]);
}

// load one K=32 chunk (4 anchors) into rotating slot sl
#define LOADCH(sb, KA, ci, sl)                                       \
  pre[sl][0] = *(const bf16x8*)((sb) + 0 * (KA) + (ci) * 32);        \
  pre[sl][1] = *(const bf16x8*)((sb) + 1 * (KA) + (ci) * 32);        \
  pre[sl][2] = *(const bf16x8*)((sb) + 2 * (KA) + (ci) * 32);        \
  pre[sl][3] = *(const bf16x8*)((sb) + 3 * (KA) + (ci) * 32)

#define MFMA4()                                                            \
  acc0 = __builtin_amdgcn_mfma_f32_16x16x32_bf16(av, b0v, acc0, 0, 0, 0);  \
  acc1 = __builtin_amdgcn_mfma_f32_16x16x32_bf16(av, b1v, acc1, 0, 0, 0);  \
  acc2 = __builtin_amdgcn_mfma_f32_16x16x32_bf16(av, b2v, acc2, 0, 0, 0);  \
  acc3 = __builtin_amdgcn_mfma_f32_16x16x32_bf16(av, b3v, acc3, 0, 0, 0)

#define TAKE(sl)                                                     \
  bf16x8 b0v = pre[sl][0], b1v = pre[sl][1],                         \
         b2v = pre[sl][2], b3v = pre[sl][3]

// mid-layer epilogue: anchor-combine (bias already in acc) + ELU + bf16 write
static __device__ __forceinline__ void epi_mid(f32x4 a0, f32x4 a1, f32x4 a2,
                                               f32x4 a3, const float cbr[4][4],
                                               int colg, int quad, char* outBuf) {
  const int g = colg >> 3;
  const int j2 = (colg & 7) * 2;
#pragma unroll
  for (int r = 0; r < 4; ++r) {
    const int m = quad * 4 + r;
    float y = cbr[r][0] * a0[r] + cbr[r][1] * a1[r] +
              cbr[r][2] * a2[r] + cbr[r][3] * a3[r];
    float a = y > 0.0f ? y : (__expf(y) - 1.0f);  // ELU
    *(unsigned short*)(outBuf + m * 512 + (((g ^ (m & 15)) << 4) + j2)) = f2bf(a);
  }
}

__global__ __launch_bounds__(1024, 4) void k_fused(
    const float* __restrict__ x, const float* __restrict__ phase,
    const unsigned short* __restrict__ Wt0, const float* __restrict__ b0,
    const unsigned short* __restrict__ Wt1, const float* __restrict__ b1,
    const unsigned short* __restrict__ Wt2, const float* __restrict__ b2,
    float* __restrict__ out) {
  __shared__ __align__(1024) char smem[LDS_TOT];

  const int tid = threadIdx.x;
  const int lane = tid & 63;
  const int wid = tid >> 6;     // 0..15
  const int col = lane & 15;
  const int quad = lane >> 4;
  const int m0 = blockIdx.x * 16;
  const int colg = wid * 16 + col;           // L0/L1 output column
  const int cg = wid & 7, kh = wid >> 3;     // L2: col-group + K-half
  const int colg2 = cg * 16 + col;
  const int hi16 = (col & 12) << 4;          // A-swizzle high bits
  const int lb = (quad ^ (col & 3)) << 4;    // A-swizzle low bits

  // per-lane B source bases (lane holds 16B of col colg, k-offset quad*8)
  const unsigned short* sb0 = Wt0 + (size_t)colg * 512 + quad * 8;
  const unsigned short* sb1 = Wt1 + (size_t)colg * 1024 + quad * 8;
  const unsigned short* sb2 = Wt2 + (size_t)colg2 * 1024 + kh * 128 + quad * 8;

  // ---- prologue global loads ----
  float4 xv = {0.f, 0.f, 0.f, 0.f};
  if (tid < 512)
    xv = *(const float4*)(x + (size_t)(m0 + (tid >> 5)) * 128 + (tid & 31) * 4);

  float bva[4], bvb[4], bvc[4];
#pragma unroll
  for (int k = 0; k < 4; ++k) {
    bva[k] = b0[k * 256 + colg];
    bvb[k] = b1[k * 256 + colg];
    bvc[k] = b2[k * 128 + colg2];
  }
  float ph[4];
#pragma unroll
  for (int r = 0; r < 4; ++r) ph[r] = phase[m0 + quad * 4 + r];

  // ---- start the register B pipeline: chunks 0..2 of L0 ----
  bf16x8 pre[3][4];
  LOADCH(sb0, 128, 0, 0);
  LOADCH(sb0, 128, 1, 1);
  LOADCH(sb0, 128, 2, 2);

  // per-lane Catmull coeffs for its 4 rows
  float cbr[4][4];
#pragma unroll
  for (int r = 0; r < 4; ++r) catmull(ph[r], cbr[r]);

  // ---- build A0: unscaled bf16 x, granule-swizzled (g ^ (row&15)) ----
  if (tid < 512) {
    const int row = tid >> 5, seg = tid & 31;
    const int g = seg >> 1, h = seg & 1;
    short4 hv;
    hv.x = (short)f2bf(xv.x); hv.y = (short)f2bf(xv.y);
    hv.z = (short)f2bf(xv.z); hv.w = (short)f2bf(xv.w);
    *(short4*)(smem + LDS_A0 + row * 256 + ((g ^ (row & 15)) << 4) + h * 8) = hv;
  }
  bar_lgkm();

  f32x4 acc0, acc1, acc2, acc3;

  // ---- layer 0: A0 (K=128 x 4 anchors) @ Wt0 -> A1. steps s=0..3 ----
  {
    acc0 = (f32x4){bva[0], bva[0], bva[0], bva[0]};
    acc1 = (f32x4){bva[1], bva[1], bva[1], bva[1]};
    acc2 = (f32x4){bva[2], bva[2], bva[2], bva[2]};
    acc3 = (f32x4){bva[3], bva[3], bva[3], bva[3]};
    const char* aL = smem + LDS_A0 + col * 256 + lb;
#pragma unroll
    for (int i = 0; i < 4; ++i) {
      const int sl = i % 3;
      TAKE(sl);
      if (i == 0)      { LOADCH(sb0, 128, 3, 0); }   // L0 c3
      else if (i == 1) { LOADCH(sb1, 256, 0, 1); }   // L1 c0
      else if (i == 2) { LOADCH(sb1, 256, 1, 2); }   // L1 c1
      else             { LOADCH(sb1, 256, 2, 0); }   // L1 c2
      bf16x8 av = *(const bf16x8*)(aL + ((i << 6) ^ hi16));
      MFMA4();
    }
    epi_mid(acc0, acc1, acc2, acc3, cbr, colg, quad, smem + LDS_A1);
  }
  bar_lgkm();

  // ---- layer 1: A1 (K=256 x 4 anchors) @ Wt1 -> A2. steps s=4..11 ----
  {
    acc0 = (f32x4){bvb[0], bvb[0], bvb[0], bvb[0]};
    acc1 = (f32x4){bvb[1], bvb[1], bvb[1], bvb[1]};
    acc2 = (f32x4){bvb[2], bvb[2], bvb[2], bvb[2]};
    acc3 = (f32x4){bvb[3], bvb[3], bvb[3], bvb[3]};
    const char* aL = smem + LDS_A1 + col * 512 + lb;
#pragma unroll
    for (int i = 0; i < 8; ++i) {
      const int sl = (i + 1) % 3;
      TAKE(sl);
      if (i < 5)       { LOADCH(sb1, 256, i + 3, sl); }  // L1 c3..c7
      else if (i == 5) { LOADCH(sb2, 256, 0, sl); }      // L2 c0
      else if (i == 6) { LOADCH(sb2, 256, 1, sl); }      // L2 c1
      else             { LOADCH(sb2, 256, 2, sl); }      // L2 c2
      bf16x8 av = *(const bf16x8*)(aL + ((i << 6) ^ hi16));
      MFMA4();
    }
    epi_mid(acc0, acc1, acc2, acc3, cbr, colg, quad, smem + LDS_A2);
  }
  bar_lgkm();

  // ---- layer 2: A2 (K=256 x 4 anchors) @ Wt2 -> out. steps s=12..15 ----
  {
    const float bz = 0.0f;
    acc0 = (f32x4){kh ? bz : bvc[0], kh ? bz : bvc[0], kh ? bz : bvc[0], kh ? bz : bvc[0]};
    acc1 = (f32x4){kh ? bz : bvc[1], kh ? bz : bvc[1], kh ? bz : bvc[1], kh ? bz : bvc[1]};
    acc2 = (f32x4){kh ? bz : bvc[2], kh ? bz : bvc[2], kh ? bz : bvc[2], kh ? bz : bvc[2]};
    acc3 = (f32x4){kh ? bz : bvc[3], kh ? bz : bvc[3], kh ? bz : bvc[3], kh ? bz : bvc[3]};
    const char* aL = smem + LDS_A2 + col * 512 + kh * 256 + lb;
#pragma unroll
    for (int i = 0; i < 4; ++i) {
      const int sl = i % 3;
      TAKE(sl);
      if (i == 0) { LOADCH(sb2, 256, 3, 0); }            // L2 c3
      bf16x8 av = *(const bf16x8*)(aL + ((i << 6) ^ hi16));
      MFMA4();
    }

    // anchor-combine partials (bias already inside kh==0's acc)
    float part[4];
#pragma unroll
    for (int r = 0; r < 4; ++r)
      part[r] = cbr[r][0] * acc0[r] + cbr[r][1] * acc1[r] +
                cbr[r][2] * acc2[r] + cbr[r][3] * acc3[r];

    float* red = (float*)(smem + LDS_RED);   // [8][16][17]
    if (kh) {
#pragma unroll
      for (int r = 0; r < 4; ++r)
        red[cg * 272 + (quad * 4 + r) * 17 + col] = part[r];
    }
    bar_lgkm();
    if (!kh) {
#pragma unroll
      for (int r = 0; r < 4; ++r) {
        const int m = quad * 4 + r;
        float y = part[r] + red[cg * 272 + m * 17 + col];
        out[(size_t)(m0 + m) * 128 + colg2] = y;
      }
    }
  }
}

// ---------------------------------------------------------------------------
// ws layout: Wt0 @0 (256KB), Wt1 @256KB (512KB), Wt2 @768KB (256KB). 1 MB.
// ---------------------------------------------------------------------------
extern "C" void kernel_launch(void* const* d_in, const int* in_sizes, int n_in,
                              void* d_out, int out_size, void* d_ws, size_t ws_size,
                              hipStream_t stream) {
  const float* x     = (const float*)d_in[0];
  const float* phase = (const float*)d_in[1];
  const float* w0    = (const float*)d_in[2];
  const float* b0    = (const float*)d_in[3];
  const float* w1    = (const float*)d_in[4];
  const float* b1    = (const float*)d_in[5];
  const float* w2    = (const float*)d_in[6];
  const float* b2    = (const float*)d_in[7];
  float* out = (float*)d_out;

  char* ws = (char*)d_ws;
  unsigned short* Wt0 = (unsigned short*)ws;
  unsigned short* Wt1 = (unsigned short*)(ws + 262144);
  unsigned short* Wt2 = (unsigned short*)(ws + 262144 + 524288);

  k_wt_all<<<128, dim3(32, 32), 0, stream>>>(w0, w1, w2, Wt0, Wt1, Wt2);
  k_fused<<<256, 1024, 0, stream>>>(x, phase, Wt0, b0, Wt1, b1, Wt2, b2, out);
}